// Round 10
// baseline (244.591 us; speedup 1.0000x reference)
//
#include <hip/hip_runtime.h>

// KMEANS encode+decode: B=65536, G=256, K=512, fp32.
// R15: B-stationary registers. Falsified so far: prefetch depth (R12),
// B-load count (R13), occupancy (R14: +50% waves, dur flat) -- the K-loop is
// serialized by in-order vmcnt waits (VGPR 48-64: compiler holds ~1-2 loads
// in flight and re-sinks source prefetch). Fix: REMOVE the loads. Each wave
// owns 64 codes; its whole B-slice (4 nf x 8 p = 32 halfx8 = 128 VGPR) is
// loaded ONCE per block; the tile loop has zero B loads. 1024 blocks x 512
// thr (8 waves), 4 M-tiles of 16 rows per block; 2 waves/EU, 1 block/CU --
// low occupancy BY DESIGN (nothing left to hide).
// Numerics identical to R13/R14 (same pack, hh->lh chain over ascending p;
// min/2nd-min over the same 512-value multiset with strict-< and tie->lower-k
// is iteration-order-independent), TAU=4e-3; flagged rows re-solved EXACTLY
// in R1 fp32 order by the 6x-validated inline rescue. absmax 0.0 expected.

constexpr int BATCH  = 65536;
constexpr int GDIM   = 256;   // GEMM K (features)
constexpr int KDIM   = 512;   // GEMM N (codes)
constexpr int MTILE  = 16;    // rows per tile
constexpr int TPB    = 4;     // tiles per block
constexpr int NBLK   = BATCH / (MTILE * TPB);   // 1024 blocks
constexpr float TAU  = 4e-3f;

typedef _Float16 halfx8 __attribute__((ext_vector_type(8)));
typedef float    floatx4 __attribute__((ext_vector_type(4)));

#define SPLIT1(H, L, X) { const _Float16 h_ = (_Float16)(X); (H) = h_; (L) = (_Float16)((X) - (float)h_); }

// ---------------- prep: transpose + m2 + pack (h only) ----------------
// Packed B layout (verified R4): vec ((nf*8 + p)*4 + q)*16 + n15 holds 8
// halves (k = p*32 + q*8 + j) of column n = nf*16 + n15.

__global__ __launch_bounds__(256)
void prep_kernel(const float* __restrict__ mu, float* __restrict__ muT,
                 float* __restrict__ m2,
                 halfx8* __restrict__ packh) {
    const int tid = threadIdx.x;
    const int b   = blockIdx.x;
    if (b < 512) {
        const int k = b;
        muT[k * GDIM + tid] = mu[(size_t)tid * KDIM + k];
    } else if (b == 512) {
        float s0 = 0.f, s1 = 0.f;
        for (int g = 0; g < GDIM; ++g) {
            const float a = mu[(size_t)g * KDIM + tid];
            const float c = mu[(size_t)g * KDIM + tid + 256];
            s0 += a * a; s1 += c * c;
        }
        m2[tid] = s0; m2[tid + 256] = s1;
    } else {
        const int gid = (b - 513) * 256 + tid;   // [0, 16384)
        const int n15 = gid & 15;
        const int q   = (gid >> 4) & 3;
        const int p   = (gid >> 6) & 7;
        const int nf  = gid >> 9;
        const int n   = nf * 16 + n15;
        const int k0  = p * 32 + q * 8;
        halfx8 hv;
        #pragma unroll
        for (int j = 0; j < 8; ++j) {
            const float v = mu[(size_t)(k0 + j) * KDIM + n];
            hv[j] = (_Float16)v;
        }
        packh[gid] = hv;
    }
}

// ---------------- main: B-stationary gemm + argmin + recon + rescue ------

__global__ __launch_bounds__(512) __attribute__((amdgpu_waves_per_eu(2, 2)))
void gemm_argmin_mfma(const float* __restrict__ images, const float* __restrict__ mu,
                      const halfx8* __restrict__ packh,
                      const float* __restrict__ m2g,
                      const float* __restrict__ muT,
                      float* __restrict__ out) {
    // A staged as f16 hi/lo split. Row stride 33 vecs (528 B, 16B-aligned).
    constexpr int ASTR = 33;                // halfx8 vecs per row
    __shared__ halfx8 AhL[MTILE * ASTR];
    __shared__ halfx8 AlL[MTILE * ASTR];
    __shared__ float sd1[8][MTILE];
    __shared__ float sd2[8][MTILE];
    __shared__ int   sk1[8][MTILE];
    __shared__ int   kb[MTILE];
    __shared__ int   slist[MTILE];
    __shared__ int   scount;
    __shared__ float xs[GDIM];
    __shared__ float rsd[256];
    __shared__ int   rsk[256];

    const int tid  = threadIdx.x;
    const int wave = tid >> 6;              // 0..7 -> codes wave*64..+63
    const int lane = tid & 63;
    const int q    = lane >> 4;
    const int l15  = lane & 15;

    // ---- B preload, ONCE per block: wave's 64-code slice in registers ----
    // bidx(nf,p) = ((nfg*8 + p)*4 + q)*16 + l15, nfg = wave*4 + nf.
    halfx8 B[4][8];
    #pragma unroll
    for (int nf = 0; nf < 4; ++nf)
        #pragma unroll
        for (int p = 0; p < 8; ++p)
            B[nf][p] = packh[(((wave * 4 + nf) * 8 + p) * 4 + q) * 16 + l15];

    // m2 for this wave's codes (codebook-constant across tiles)
    float m2v[4];
    #pragma unroll
    for (int nf = 0; nf < 4; ++nf)
        m2v[nf] = m2g[wave * 64 + nf * 16 + l15];

    for (int t = 0; t < TPB; ++t) {
        const int m0 = (blockIdx.x * TPB + t) * MTILE;

        __syncthreads();                    // LDS/scount reuse vs prev tile
        if (tid == 0) scount = 0;

        // ---- stage + split A (512 threads, 1 chunk each) ----
        {
            const int row = tid >> 5;       // 0..15
            const int kc  = tid & 31;       // 8-float chunk within row
            const float* src = images + (size_t)(m0 + row) * GDIM + kc * 8;
            const float4 v0 = *(const float4*)(src);
            const float4 v1 = *(const float4*)(src + 4);
            halfx8 hv, lv;
            SPLIT1(hv[0], lv[0], v0.x)
            SPLIT1(hv[1], lv[1], v0.y)
            SPLIT1(hv[2], lv[2], v0.z)
            SPLIT1(hv[3], lv[3], v0.w)
            SPLIT1(hv[4], lv[4], v1.x)
            SPLIT1(hv[5], lv[5], v1.y)
            SPLIT1(hv[6], lv[6], v1.z)
            SPLIT1(hv[7], lv[7], v1.w)
            AhL[row * ASTR + kc] = hv;
            AlL[row * ASTR + kc] = lv;
        }
        __syncthreads();

        // ---- K-loop: pure LDS + register MFMA, zero global loads ----
        floatx4 acc[4] = {};
        #pragma unroll
        for (int p = 0; p < 8; ++p) {
            const int off = l15 * ASTR + p * 4 + q;
            const halfx8 Ah = AhL[off];
            const halfx8 Al = AlL[off];
            #pragma unroll
            for (int nf = 0; nf < 4; ++nf) {
                acc[nf] = __builtin_amdgcn_mfma_f32_16x16x32_f16(Ah, B[nf][p], acc[nf], 0, 0, 0);
                acc[nf] = __builtin_amdgcn_mfma_f32_16x16x32_f16(Al, B[nf][p], acc[nf], 0, 0, 0);
            }
        }

        // ---- rank on s = m2 - 2*xm (x2 row-constant, argmin-invariant) ----
        // C layout (verified R4): col = lane&15 (code), row = q*4 + reg.
        float d1[4], d2[4];
        int   k1[4];
        #pragma unroll
        for (int r = 0; r < 4; ++r) { d1[r] = 3.402823466e+38f; d2[r] = 3.402823466e+38f; k1[r] = 0; }

        #pragma unroll
        for (int nf = 0; nf < 4; ++nf) {
            const int kc = wave * 64 + nf * 16 + l15;
            #pragma unroll
            for (int r = 0; r < 4; ++r) {
                const float d = m2v[nf] - 2.0f * acc[nf][r];
                if (d < d1[r]) { d2[r] = d1[r]; d1[r] = d; k1[r] = kc; }
                else if (d < d2[r]) { d2[r] = d; }
            }
        }

        // butterfly across the 16 lanes of each quad; tie -> lower k
        #pragma unroll
        for (int s = 1; s < 16; s <<= 1) {
            #pragma unroll
            for (int r = 0; r < 4; ++r) {
                const float od1 = __shfl_xor(d1[r], s, 64);
                const int   ok1 = __shfl_xor(k1[r], s, 64);
                const float od2 = __shfl_xor(d2[r], s, 64);
                const bool take = (od1 < d1[r]) || (od1 == d1[r] && ok1 < k1[r]);
                const float loser = take ? d1[r] : od1;
                if (take) { d1[r] = od1; k1[r] = ok1; }
                const float m2x = (od2 < d2[r]) ? od2 : d2[r];
                d2[r] = (loser < m2x) ? loser : m2x;
            }
        }

        if (l15 == 0) {
            #pragma unroll
            for (int r = 0; r < 4; ++r) {
                const int ml = q * 4 + r;           // row within tile
                sd1[wave][ml] = d1[r];
                sd2[wave][ml] = d2[r];
                sk1[wave][ml] = k1[r];
            }
        }
        __syncthreads();

        if (tid < MTILE) {
            float D1 = sd1[0][tid], D2 = sd2[0][tid];
            int   K1 = sk1[0][tid];
            #pragma unroll
            for (int w = 1; w < 8; ++w) {      // ascending wave = ascending k
                const float od1 = sd1[w][tid], od2 = sd2[w][tid];
                const int   ok1 = sk1[w][tid];
                if (od1 < D1) { D2 = (D1 < od2) ? D1 : od2; D1 = od1; K1 = ok1; }
                else          { D2 = (od1 < D2) ? od1 : D2; }
            }
            kb[tid] = K1;
            if (D2 - D1 < TAU) {
                const int i = atomicAdd(&scount, 1);
                slist[i] = tid;                // local row index
            }
        }
        __syncthreads();

        // ---- fused recon: out rows from muT (L2-hot) ----
        float4* out4 = (float4*)(out + (size_t)m0 * GDIM);
        const float4* muT4 = (const float4*)muT;
        #pragma unroll
        for (int i = 0; i < 2; ++i) {
            const int idx = tid + i * 512;
            const int rr = idx >> 6, cc = idx & 63;
            out4[idx] = muT4[(size_t)kb[rr] * (GDIM / 4) + cc];
        }

        // ---- inline rescue (validated R7/R9-R11/R13/R14): exact R1 fp32 ----
        const int cnt = scount;
        for (int i = 0; i < cnt; ++i) {
            const int row = m0 + slist[i];
            if (tid < 256) xs[tid] = images[(size_t)row * GDIM + tid];
            __syncthreads();
            if (tid < 256) {
                // x2 in the proven g-ascending serial order
                float x2 = 0.f;
                for (int g = 0; g < GDIM; ++g) x2 += xs[g] * xs[g];
                // codes tid and tid+256: independent g-ascending fp32 chains
                float sA = 0.f, sB = 0.f;
                for (int g = 0; g < GDIM; ++g) {
                    const float xv = xs[g];
                    const float* mp = mu + (size_t)g * KDIM;
                    sA += xv * mp[tid];
                    sB += xv * mp[tid + 256];
                }
                const float dA = (x2 - 2.0f * sA) + m2g[tid];
                const float dB = (x2 - 2.0f * sB) + m2g[tid + 256];
                float bd = dA; int bk = tid;
                if (dB < bd) { bd = dB; bk = tid + 256; }  // strict <: lower k
                rsd[tid] = bd; rsk[tid] = bk;
            }
            __syncthreads();
            for (int s = 128; s > 0; s >>= 1) {
                if (tid < s) {
                    const float db = rsd[tid + s]; const int kb2 = rsk[tid + s];
                    if (db < rsd[tid] || (db == rsd[tid] && kb2 < rsk[tid])) { rsd[tid] = db; rsk[tid] = kb2; }
                }
                __syncthreads();
            }
            const int kwin = rsk[0];
            if (tid < 256) out[(size_t)row * GDIM + tid] = muT[(size_t)kwin * GDIM + tid];
            __syncthreads();
        }
    }
}

// ---------------- fallback (R1 kernel, no workspace) ----------------

constexpr int FROWS = 64, FXSTR = GDIM + 1;

__global__ __launch_bounds__(256)
void kmeans_fallback(const float* __restrict__ images, const float* __restrict__ mu,
                     float* __restrict__ out) {
    __shared__ float xsf[FROWS * FXSTR];
    __shared__ float m2s[KDIM];
    __shared__ float bd_s[4][FROWS];
    __shared__ int   bk_s[4][FROWS];
    __shared__ int   kbest_s[FROWS];
    const int tid = threadIdx.x;
    const long long b0 = (long long)blockIdx.x * FROWS;
    {
        const float4* img4 = (const float4*)(images + b0 * GDIM);
        #pragma unroll
        for (int i = 0; i < 16; ++i) {
            const int idx = tid + i * 256;
            const int r = idx >> 6, c = idx & 63;
            const float4 v = img4[idx];
            float* dst = &xsf[r * FXSTR + c * 4];
            dst[0] = v.x; dst[1] = v.y; dst[2] = v.z; dst[3] = v.w;
        }
    }
    {
        float s0 = 0.f, s1 = 0.f;
        for (int g = 0; g < GDIM; ++g) {
            const float a = mu[(size_t)g * KDIM + tid];
            const float b = mu[(size_t)g * KDIM + tid + 256];
            s0 += a * a; s1 += b * b;
        }
        m2s[tid] = s0; m2s[tid + 256] = s1;
    }
    __syncthreads();
    const int r = tid & (FROWS - 1), ch = tid >> 6;
    const float* xrow = &xsf[r * FXSTR];
    float x2 = 0.f;
    #pragma unroll 8
    for (int g = 0; g < GDIM; ++g) x2 += xrow[g] * xrow[g];
    float bestd = 3.402823466e+38f; int bestk = 0;
    const int k0base = ch * (KDIM / 4);
    for (int kt = 0; kt < KDIM / 4; kt += 8) {
        const int k0 = k0base + kt;
        float a8[8];
        #pragma unroll
        for (int j = 0; j < 8; ++j) a8[j] = 0.f;
        const float* mp = mu + k0;
        #pragma unroll 4
        for (int g = 0; g < GDIM; ++g) {
            const float xv = xrow[g];
            const float4 a = *(const float4*)(mp + (size_t)g * KDIM);
            const float4 b = *(const float4*)(mp + (size_t)g * KDIM + 4);
            a8[0] += xv * a.x; a8[1] += xv * a.y; a8[2] += xv * a.z; a8[3] += xv * a.w;
            a8[4] += xv * b.x; a8[5] += xv * b.y; a8[6] += xv * b.z; a8[7] += xv * b.w;
        }
        #pragma unroll
        for (int j = 0; j < 8; ++j) {
            const float t = x2 - 2.0f * a8[j];
            const float d = t + m2s[k0 + j];
            if (d < bestd) { bestd = d; bestk = k0 + j; }
        }
    }
    bd_s[ch][r] = bestd; bk_s[ch][r] = bestk;
    __syncthreads();
    if (tid < FROWS) {
        float bd = bd_s[0][tid]; int bk = bk_s[0][tid];
        #pragma unroll
        for (int c = 1; c < 4; ++c)
            if (bd_s[c][tid] < bd) { bd = bd_s[c][tid]; bk = bk_s[c][tid]; }
        kbest_s[tid] = bk;
    }
    __syncthreads();
    for (int i = tid; i < FROWS * GDIM; i += 256) {
        const int rr = i >> 8, gg = i & (GDIM - 1);
        out[b0 * GDIM + i] = mu[(size_t)gg * KDIM + kbest_s[rr]];
    }
}

// ---------------- launch ----------------

extern "C" void kernel_launch(void* const* d_in, const int* in_sizes, int n_in,
                              void* d_out, int out_size, void* d_ws, size_t ws_size,
                              hipStream_t stream) {
    const float* images = (const float*)d_in[0];
    const float* mu     = (const float*)d_in[1];
    float* out = (float*)d_out;

    float* ws     = (float*)d_ws;
    float* muT    = ws;                          // 131072 floats
    float* m2     = ws + 131072;                 // 512
    halfx8* packh = (halfx8*)(ws + 131584);      // 65536 floats (16384 vecs)
    const size_t need = (size_t)197120 * sizeof(float);

    if (d_ws != nullptr && ws_size >= need) {
        prep_kernel<<<577, 256, 0, stream>>>(mu, muT, m2, packh);
        gemm_argmin_mfma<<<NBLK, 512, 0, stream>>>(images, mu, packh,
                                                   m2, muT, out);
    } else {
        kmeans_fallback<<<BATCH / 64, 256, 0, stream>>>(images, mu, out);
    }
}

// Round 11
// 199.398 us; speedup vs baseline: 1.2266x; 1.2266x over previous
//
#include <hip/hip_runtime.h>

// KMEANS encode+decode: B=65536, G=256, K=512, fp32.
// R16: return to R11 (best measured: total 187.9us, gemm 104-107us) plus one
// zero-risk fix: hoist the epilogue's 8 m2g loads ABOVE the K-loop so their
// L2 latency hides under ~2300cy of MFMA (values identical; m2g written by
// the prior dispatch). Structural ledger (all falsified): R12 prefetch
// (compiler re-sinks), R13 halved B-loads (flat), R14 +50% occupancy (flat),
// R15 B-stationary (1 blk/CU, much worse), R9/R10 single-dispatch (scratch /
// L2-invalidate poison). The remaining total-vs-gemm gap (~70us) is
// harness-fixed (out memset + input re-poison restores between iterations).
// Numerics: 3-chain split (hh+hl+lh, p ascending, verified pack layout),
// rank on s = m2 - 2*xm, strict-< / tie->lower-k, TAU=2e-3 with the
// 6x-validated exact-R1-order inline rescue. absmax 0.0 in R1-R7, R9-R15.

constexpr int BATCH  = 65536;
constexpr int GDIM   = 256;   // GEMM K (features)
constexpr int KDIM   = 512;   // GEMM N (codes)
constexpr int NTILES = BATCH / 32;   // 2048 tiles of 32 rows
constexpr float TAU  = 2e-3f;

typedef _Float16 halfx8 __attribute__((ext_vector_type(8)));
typedef float    floatx4 __attribute__((ext_vector_type(4)));

#define SPLIT1(H, L, X) { const _Float16 h_ = (_Float16)(X); (H) = h_; (L) = (_Float16)((X) - (float)h_); }

// ---------------- prep: transpose + m2 + pack (R6-proven) ----------------
// Packed B layout (verified R4): vec ((nf*8 + p)*4 + q)*16 + n15 holds 8
// halves (k = p*32 + q*8 + j) of column n = nf*16 + n15.

__global__ __launch_bounds__(256)
void prep_kernel(const float* __restrict__ mu, float* __restrict__ muT,
                 float* __restrict__ m2,
                 halfx8* __restrict__ packh, halfx8* __restrict__ packl) {
    const int tid = threadIdx.x;
    const int b   = blockIdx.x;
    if (b < 512) {
        const int k = b;
        muT[k * GDIM + tid] = mu[(size_t)tid * KDIM + k];
    } else if (b == 512) {
        float s0 = 0.f, s1 = 0.f;
        for (int g = 0; g < GDIM; ++g) {
            const float a = mu[(size_t)g * KDIM + tid];
            const float c = mu[(size_t)g * KDIM + tid + 256];
            s0 += a * a; s1 += c * c;
        }
        m2[tid] = s0; m2[tid + 256] = s1;
    } else {
        const int gid = (b - 513) * 256 + tid;   // [0, 16384)
        const int n15 = gid & 15;
        const int q   = (gid >> 4) & 3;
        const int p   = (gid >> 6) & 7;
        const int nf  = gid >> 9;
        const int n   = nf * 16 + n15;
        const int k0  = p * 32 + q * 8;
        halfx8 hv, lv;
        #pragma unroll
        for (int j = 0; j < 8; ++j) {
            const float v = mu[(size_t)(k0 + j) * KDIM + n];
            const _Float16 h = (_Float16)v;
            hv[j] = h;
            lv[j] = (_Float16)(v - (float)h);
        }
        packh[gid] = hv;
        packl[gid] = lv;
    }
}

// ---------------- main: gemm + argmin + recon + inline rescue ------------

__global__ __launch_bounds__(256) __attribute__((amdgpu_waves_per_eu(3, 4)))
void gemm_argmin_mfma(const float* __restrict__ images, const float* __restrict__ mu,
                      const halfx8* __restrict__ packh,
                      const halfx8* __restrict__ packl,
                      const float* __restrict__ m2g,
                      const float* __restrict__ muT,
                      float* __restrict__ out) {
    // A staged as f16 hi/lo split. Row stride 33 vecs (528 B, 16B-aligned):
    // +4-bank skew per row keeps fragment ds_read_b128 conflicts minor.
    constexpr int ASTR = 33;                // halfx8 vecs per row
    __shared__ halfx8 AhL[32 * ASTR];
    __shared__ halfx8 AlL[32 * ASTR];
    __shared__ float sd1[4][32];
    __shared__ float sd2[4][32];
    __shared__ int   sk1[4][32];
    __shared__ int   kb[32];
    __shared__ int   slist[32];
    __shared__ int   scount;
    __shared__ float xs[GDIM];
    __shared__ float rsd[256];
    __shared__ int   rsk[256];

    const int tid  = threadIdx.x;
    const int wave = tid >> 6;
    const int lane = tid & 63;
    const int q    = lane >> 4;
    const int l15  = lane & 15;
    const int m0   = blockIdx.x * 32;

    if (tid == 0) scount = 0;

    // ---- m2 hoist: issue these 8 L2 loads now; they complete under the
    // K-loop's MFMA. Values identical to the old post-loop loads.
    float m2v[8];
    #pragma unroll
    for (int nf = 0; nf < 8; ++nf)
        m2v[nf] = m2g[wave * 128 + nf * 16 + l15];

    // ---- stage + split A once per tile (each row split exactly once) ----
    #pragma unroll
    for (int i = 0; i < 4; ++i) {
        const int cid = tid + i * 256;      // 0..1023
        const int row = cid >> 5;           // 0..31
        const int kc  = cid & 31;           // 8-float chunk within row
        const float* src = images + (size_t)(m0 + row) * GDIM + kc * 8;
        const float4 v0 = *(const float4*)(src);
        const float4 v1 = *(const float4*)(src + 4);
        halfx8 hv, lv;
        SPLIT1(hv[0], lv[0], v0.x)
        SPLIT1(hv[1], lv[1], v0.y)
        SPLIT1(hv[2], lv[2], v0.z)
        SPLIT1(hv[3], lv[3], v0.w)
        SPLIT1(hv[4], lv[4], v1.x)
        SPLIT1(hv[5], lv[5], v1.y)
        SPLIT1(hv[6], lv[6], v1.z)
        SPLIT1(hv[7], lv[7], v1.w)
        AhL[row * ASTR + kc] = hv;
        AlL[row * ASTR + kc] = lv;
    }
    __syncthreads();

    floatx4 acc[2][8] = {};

    // K-loop (R6/R11 body, verbatim): no barriers. A-frag: m = lane&15,
    // k = q*8 + j; vec index for (row, p, q) = row*ASTR + p*4 + q.
    for (int p = 0; p < 8; ++p) {
        halfx8 Ah[2], Al[2];
        #pragma unroll
        for (int mf = 0; mf < 2; ++mf) {
            const int off = (mf * 16 + l15) * ASTR + p * 4 + q;
            Ah[mf] = AhL[off];
            Al[mf] = AlL[off];
        }
        #pragma unroll
        for (int nf = 0; nf < 8; ++nf) {
            const int nfg = wave * 8 + nf;
            const int bidx = ((nfg * 8 + p) * 4 + q) * 16 + l15;
            const halfx8 Bh = packh[bidx];
            const halfx8 Bl = packl[bidx];
            #pragma unroll
            for (int mf = 0; mf < 2; ++mf) {
                acc[mf][nf] = __builtin_amdgcn_mfma_f32_16x16x32_f16(Ah[mf], Bh, acc[mf][nf], 0, 0, 0);
                acc[mf][nf] = __builtin_amdgcn_mfma_f32_16x16x32_f16(Ah[mf], Bl, acc[mf][nf], 0, 0, 0);
                acc[mf][nf] = __builtin_amdgcn_mfma_f32_16x16x32_f16(Al[mf], Bh, acc[mf][nf], 0, 0, 0);
            }
        }
    }

    // ---- epilogue: rank on s = m2 - 2*xm (x2 row-constant) ----
    // C layout (verified R4): col = lane&15 (n_local), row = q*4 + reg.
    float d1[2][4], d2[2][4];
    int   k1[2][4];
    #pragma unroll
    for (int mf = 0; mf < 2; ++mf)
        #pragma unroll
        for (int r = 0; r < 4; ++r) { d1[mf][r] = 3.402823466e+38f; d2[mf][r] = 3.402823466e+38f; k1[mf][r] = 0; }

    #pragma unroll
    for (int nf = 0; nf < 8; ++nf) {
        const int kc = wave * 128 + nf * 16 + l15;
        #pragma unroll
        for (int mf = 0; mf < 2; ++mf)
            #pragma unroll
            for (int r = 0; r < 4; ++r) {
                const float d = m2v[nf] - 2.0f * acc[mf][nf][r];
                if (d < d1[mf][r]) { d2[mf][r] = d1[mf][r]; d1[mf][r] = d; k1[mf][r] = kc; }
                else if (d < d2[mf][r]) { d2[mf][r] = d; }
            }
    }

    // butterfly across the 16 lanes of each quad; tie -> lower k
    #pragma unroll
    for (int s = 1; s < 16; s <<= 1) {
        #pragma unroll
        for (int mf = 0; mf < 2; ++mf)
            #pragma unroll
            for (int r = 0; r < 4; ++r) {
                const float od1 = __shfl_xor(d1[mf][r], s, 64);
                const int   ok1 = __shfl_xor(k1[mf][r], s, 64);
                const float od2 = __shfl_xor(d2[mf][r], s, 64);
                const bool take = (od1 < d1[mf][r]) || (od1 == d1[mf][r] && ok1 < k1[mf][r]);
                const float loser = take ? d1[mf][r] : od1;
                if (take) { d1[mf][r] = od1; k1[mf][r] = ok1; }
                const float m2x = (od2 < d2[mf][r]) ? od2 : d2[mf][r];
                d2[mf][r] = (loser < m2x) ? loser : m2x;
            }
    }

    if (l15 == 0) {
        #pragma unroll
        for (int mf = 0; mf < 2; ++mf)
            #pragma unroll
            for (int r = 0; r < 4; ++r) {
                const int ml = mf * 16 + q * 4 + r;     // row within tile
                sd1[wave][ml] = d1[mf][r];
                sd2[wave][ml] = d2[mf][r];
                sk1[wave][ml] = k1[mf][r];
            }
    }
    __syncthreads();

    if (tid < 32) {
        float D1 = sd1[0][tid], D2 = sd2[0][tid];
        int   K1 = sk1[0][tid];
        #pragma unroll
        for (int w = 1; w < 4; ++w) {          // ascending wave = ascending k
            const float od1 = sd1[w][tid], od2 = sd2[w][tid];
            const int   ok1 = sk1[w][tid];
            if (od1 < D1) { D2 = (D1 < od2) ? D1 : od2; D1 = od1; K1 = ok1; }
            else          { D2 = (od1 < D2) ? od1 : D2; }
        }
        kb[tid] = K1;
        if (D2 - D1 < TAU) {
            const int i = atomicAdd(&scount, 1);
            slist[i] = tid;                    // local row index
        }
    }
    __syncthreads();

    // ---- fused recon: out rows from muT (L2-hot) ----
    float4* out4 = (float4*)(out + (size_t)m0 * GDIM);
    const float4* muT4 = (const float4*)muT;
    #pragma unroll
    for (int i = 0; i < 8; ++i) {
        const int idx = tid + i * 256;
        const int rr = idx >> 6, cc = idx & 63;
        out4[idx] = muT4[(size_t)kb[rr] * (GDIM / 4) + cc];
    }

    // ---- inline rescue (validated R7/R9-R11/R13-R15): exact R1-order fp32 --
    // The first barrier below drains the recon stores (vmcnt(0) before
    // s_barrier), so the overwrite is ordered after recon.
    const int cnt = scount;
    for (int i = 0; i < cnt; ++i) {
        const int row = m0 + slist[i];
        xs[tid] = images[(size_t)row * GDIM + tid];
        __syncthreads();
        // x2 in the proven g-ascending serial order
        float x2 = 0.f;
        for (int g = 0; g < GDIM; ++g) x2 += xs[g] * xs[g];
        // codes tid and tid+256: independent g-ascending fp32 chains
        float sA = 0.f, sB = 0.f;
        for (int g = 0; g < GDIM; ++g) {
            const float xv = xs[g];
            const float* mp = mu + (size_t)g * KDIM;
            sA += xv * mp[tid];
            sB += xv * mp[tid + 256];
        }
        const float dA = (x2 - 2.0f * sA) + m2g[tid];
        const float dB = (x2 - 2.0f * sB) + m2g[tid + 256];
        float bd = dA; int bk = tid;
        if (dB < bd) { bd = dB; bk = tid + 256; }      // strict < keeps lower k
        rsd[tid] = bd; rsk[tid] = bk;
        __syncthreads();
        for (int s = 128; s > 0; s >>= 1) {
            if (tid < s) {
                const float db = rsd[tid + s]; const int kb2 = rsk[tid + s];
                if (db < rsd[tid] || (db == rsd[tid] && kb2 < rsk[tid])) { rsd[tid] = db; rsk[tid] = kb2; }
            }
            __syncthreads();
        }
        const int kwin = rsk[0];
        out[(size_t)row * GDIM + tid] = muT[(size_t)kwin * GDIM + tid];
        __syncthreads();
    }
}

// ---------------- fallback (R1 kernel, no workspace) ----------------

constexpr int FROWS = 64, FXSTR = GDIM + 1;

__global__ __launch_bounds__(256)
void kmeans_fallback(const float* __restrict__ images, const float* __restrict__ mu,
                     float* __restrict__ out) {
    __shared__ float xsf[FROWS * FXSTR];
    __shared__ float m2s[KDIM];
    __shared__ float bd_s[4][FROWS];
    __shared__ int   bk_s[4][FROWS];
    __shared__ int   kbest_s[FROWS];
    const int tid = threadIdx.x;
    const long long b0 = (long long)blockIdx.x * FROWS;
    {
        const float4* img4 = (const float4*)(images + b0 * GDIM);
        #pragma unroll
        for (int i = 0; i < 16; ++i) {
            const int idx = tid + i * 256;
            const int r = idx >> 6, c = idx & 63;
            const float4 v = img4[idx];
            float* dst = &xsf[r * FXSTR + c * 4];
            dst[0] = v.x; dst[1] = v.y; dst[2] = v.z; dst[3] = v.w;
        }
    }
    {
        float s0 = 0.f, s1 = 0.f;
        for (int g = 0; g < GDIM; ++g) {
            const float a = mu[(size_t)g * KDIM + tid];
            const float b = mu[(size_t)g * KDIM + tid + 256];
            s0 += a * a; s1 += b * b;
        }
        m2s[tid] = s0; m2s[tid + 256] = s1;
    }
    __syncthreads();
    const int r = tid & (FROWS - 1), ch = tid >> 6;
    const float* xrow = &xsf[r * FXSTR];
    float x2 = 0.f;
    #pragma unroll 8
    for (int g = 0; g < GDIM; ++g) x2 += xrow[g] * xrow[g];
    float bestd = 3.402823466e+38f; int bestk = 0;
    const int k0base = ch * (KDIM / 4);
    for (int kt = 0; kt < KDIM / 4; kt += 8) {
        const int k0 = k0base + kt;
        float a8[8];
        #pragma unroll
        for (int j = 0; j < 8; ++j) a8[j] = 0.f;
        const float* mp = mu + k0;
        #pragma unroll 4
        for (int g = 0; g < GDIM; ++g) {
            const float xv = xrow[g];
            const float4 a = *(const float4*)(mp + (size_t)g * KDIM);
            const float4 b = *(const float4*)(mp + (size_t)g * KDIM + 4);
            a8[0] += xv * a.x; a8[1] += xv * a.y; a8[2] += xv * a.z; a8[3] += xv * a.w;
            a8[4] += xv * b.x; a8[5] += xv * b.y; a8[6] += xv * b.z; a8[7] += xv * b.w;
        }
        #pragma unroll
        for (int j = 0; j < 8; ++j) {
            const float t = x2 - 2.0f * a8[j];
            const float d = t + m2s[k0 + j];
            if (d < bestd) { bestd = d; bestk = k0 + j; }
        }
    }
    bd_s[ch][r] = bestd; bk_s[ch][r] = bestk;
    __syncthreads();
    if (tid < FROWS) {
        float bd = bd_s[0][tid]; int bk = bk_s[0][tid];
        #pragma unroll
        for (int c = 1; c < 4; ++c)
            if (bd_s[c][tid] < bd) { bd = bd_s[c][tid]; bk = bk_s[c][tid]; }
        kbest_s[tid] = bk;
    }
    __syncthreads();
    for (int i = tid; i < FROWS * GDIM; i += 256) {
        const int rr = i >> 8, gg = i & (GDIM - 1);
        out[b0 * GDIM + i] = mu[(size_t)gg * KDIM + kbest_s[rr]];
    }
}

// ---------------- launch ----------------

extern "C" void kernel_launch(void* const* d_in, const int* in_sizes, int n_in,
                              void* d_out, int out_size, void* d_ws, size_t ws_size,
                              hipStream_t stream) {
    const float* images = (const float*)d_in[0];
    const float* mu     = (const float*)d_in[1];
    float* out = (float*)d_out;

    float* ws     = (float*)d_ws;
    float* muT    = ws;                          // 131072 floats
    float* m2     = ws + 131072;                 // 512
    halfx8* packh = (halfx8*)(ws + 131584);      // 65536 floats (16384 vecs)
    halfx8* packl = (halfx8*)(ws + 197120);      // 65536 floats
    const size_t need = (size_t)262656 * sizeof(float);

    if (d_ws != nullptr && ws_size >= need) {
        prep_kernel<<<577, 256, 0, stream>>>(mu, muT, m2, packh, packl);
        gemm_argmin_mfma<<<NTILES, 256, 0, stream>>>(images, mu, packh, packl,
                                                     m2, muT, out);
    } else {
        kmeans_fallback<<<BATCH / 64, 256, 0, stream>>>(images, mu, out);
    }
}

// Round 12
// 186.744 us; speedup vs baseline: 1.3098x; 1.0678x over previous
//
#include <hip/hip_runtime.h>

// KMEANS encode+decode: B=65536, G=256, K=512, fp32.
// R17 = R11 VERBATIM (measured best: total 187.9us, gemm 104-107us, absmax
// 0.0). Final revert after the full structural ledger:
//   R12 prefetch depth      -> flat (compiler re-sinks loads, VGPR stays 64)
//   R13 halved B loads+MFMA -> flat (B stream not the limit)
//   R14 +50% occupancy      -> flat-to-worse (TLP not the limit)
//   R15 B-stationary regs   -> much worse (1 blk/CU, serial chain exposed)
//   R9/R10 dispatch fusion  -> much worse (scratch traffic / L2-invalidate)
//   R16 m2 hoist            -> worse (VGPR 64->72; live-state sensitivity)
// The gemm sits at a compiler/structure fixed point: minimal K-loop live
// state (VGPR 64) beats every hand-scheduled variant. No counter shows a
// HW roofline (all pipes ~20%); remaining total-vs-kernel gap (~70us) is
// harness-fixed inter-iteration work (out memset + re-poison restores),
// invariant across 2/3/4-dispatch structures.
// Numerics: fp16 3-chain split GEMM (hh+hl+lh, p ascending, verified pack
// layout), rank on s = m2 - 2*xm (x2 row-constant, argmin-invariant),
// strict-< / tie->lower-k; rows with top-2 gap < TAU=2e-3 re-solved EXACTLY
// in R1 fp32 order by the inline rescue (absmax 0.0 across R1-R16).

constexpr int BATCH  = 65536;
constexpr int GDIM   = 256;   // GEMM K (features)
constexpr int KDIM   = 512;   // GEMM N (codes)
constexpr int NTILES = BATCH / 32;   // 2048 tiles of 32 rows
constexpr float TAU  = 2e-3f;

typedef _Float16 halfx8 __attribute__((ext_vector_type(8)));
typedef float    floatx4 __attribute__((ext_vector_type(4)));

#define SPLIT1(H, L, X) { const _Float16 h_ = (_Float16)(X); (H) = h_; (L) = (_Float16)((X) - (float)h_); }

// ---------------- prep: transpose + m2 + pack (R6-proven) ----------------
// Packed B layout (verified R4): vec ((nf*8 + p)*4 + q)*16 + n15 holds 8
// halves (k = p*32 + q*8 + j) of column n = nf*16 + n15.

__global__ __launch_bounds__(256)
void prep_kernel(const float* __restrict__ mu, float* __restrict__ muT,
                 float* __restrict__ m2,
                 halfx8* __restrict__ packh, halfx8* __restrict__ packl) {
    const int tid = threadIdx.x;
    const int b   = blockIdx.x;
    if (b < 512) {
        const int k = b;
        muT[k * GDIM + tid] = mu[(size_t)tid * KDIM + k];
    } else if (b == 512) {
        float s0 = 0.f, s1 = 0.f;
        for (int g = 0; g < GDIM; ++g) {
            const float a = mu[(size_t)g * KDIM + tid];
            const float c = mu[(size_t)g * KDIM + tid + 256];
            s0 += a * a; s1 += c * c;
        }
        m2[tid] = s0; m2[tid + 256] = s1;
    } else {
        const int gid = (b - 513) * 256 + tid;   // [0, 16384)
        const int n15 = gid & 15;
        const int q   = (gid >> 4) & 3;
        const int p   = (gid >> 6) & 7;
        const int nf  = gid >> 9;
        const int n   = nf * 16 + n15;
        const int k0  = p * 32 + q * 8;
        halfx8 hv, lv;
        #pragma unroll
        for (int j = 0; j < 8; ++j) {
            const float v = mu[(size_t)(k0 + j) * KDIM + n];
            const _Float16 h = (_Float16)v;
            hv[j] = h;
            lv[j] = (_Float16)(v - (float)h);
        }
        packh[gid] = hv;
        packl[gid] = lv;
    }
}

// ---------------- main: gemm + argmin + recon + inline rescue ------------

__global__ __launch_bounds__(256) __attribute__((amdgpu_waves_per_eu(3, 4)))
void gemm_argmin_mfma(const float* __restrict__ images, const float* __restrict__ mu,
                      const halfx8* __restrict__ packh,
                      const halfx8* __restrict__ packl,
                      const float* __restrict__ m2g,
                      const float* __restrict__ muT,
                      float* __restrict__ out) {
    // A staged as f16 hi/lo split. Row stride 33 vecs (528 B, 16B-aligned):
    // +4-bank skew per row keeps fragment ds_read_b128 conflicts minor.
    constexpr int ASTR = 33;                // halfx8 vecs per row
    __shared__ halfx8 AhL[32 * ASTR];
    __shared__ halfx8 AlL[32 * ASTR];
    __shared__ float sd1[4][32];
    __shared__ float sd2[4][32];
    __shared__ int   sk1[4][32];
    __shared__ int   kb[32];
    __shared__ int   slist[32];
    __shared__ int   scount;
    __shared__ float xs[GDIM];
    __shared__ float rsd[256];
    __shared__ int   rsk[256];

    const int tid  = threadIdx.x;
    const int wave = tid >> 6;
    const int lane = tid & 63;
    const int q    = lane >> 4;
    const int l15  = lane & 15;
    const int m0   = blockIdx.x * 32;

    if (tid == 0) scount = 0;

    // ---- stage + split A once per tile (each row split exactly once) ----
    #pragma unroll
    for (int i = 0; i < 4; ++i) {
        const int cid = tid + i * 256;      // 0..1023
        const int row = cid >> 5;           // 0..31
        const int kc  = cid & 31;           // 8-float chunk within row
        const float* src = images + (size_t)(m0 + row) * GDIM + kc * 8;
        const float4 v0 = *(const float4*)(src);
        const float4 v1 = *(const float4*)(src + 4);
        halfx8 hv, lv;
        SPLIT1(hv[0], lv[0], v0.x)
        SPLIT1(hv[1], lv[1], v0.y)
        SPLIT1(hv[2], lv[2], v0.z)
        SPLIT1(hv[3], lv[3], v0.w)
        SPLIT1(hv[4], lv[4], v1.x)
        SPLIT1(hv[5], lv[5], v1.y)
        SPLIT1(hv[6], lv[6], v1.z)
        SPLIT1(hv[7], lv[7], v1.w)
        AhL[row * ASTR + kc] = hv;
        AlL[row * ASTR + kc] = lv;
    }
    __syncthreads();

    floatx4 acc[2][8] = {};

    // K-loop (R6/R11 body, verbatim): no barriers. A-frag: m = lane&15,
    // k = q*8 + j; vec index for (row, p, q) = row*ASTR + p*4 + q.
    for (int p = 0; p < 8; ++p) {
        halfx8 Ah[2], Al[2];
        #pragma unroll
        for (int mf = 0; mf < 2; ++mf) {
            const int off = (mf * 16 + l15) * ASTR + p * 4 + q;
            Ah[mf] = AhL[off];
            Al[mf] = AlL[off];
        }
        #pragma unroll
        for (int nf = 0; nf < 8; ++nf) {
            const int nfg = wave * 8 + nf;
            const int bidx = ((nfg * 8 + p) * 4 + q) * 16 + l15;
            const halfx8 Bh = packh[bidx];
            const halfx8 Bl = packl[bidx];
            #pragma unroll
            for (int mf = 0; mf < 2; ++mf) {
                acc[mf][nf] = __builtin_amdgcn_mfma_f32_16x16x32_f16(Ah[mf], Bh, acc[mf][nf], 0, 0, 0);
                acc[mf][nf] = __builtin_amdgcn_mfma_f32_16x16x32_f16(Ah[mf], Bl, acc[mf][nf], 0, 0, 0);
                acc[mf][nf] = __builtin_amdgcn_mfma_f32_16x16x32_f16(Al[mf], Bh, acc[mf][nf], 0, 0, 0);
            }
        }
    }

    // ---- epilogue: rank on s = m2 - 2*xm (x2 row-constant) ----
    // C layout (verified R4): col = lane&15 (n_local), row = q*4 + reg.
    float m2v[8];
    #pragma unroll
    for (int nf = 0; nf < 8; ++nf)
        m2v[nf] = m2g[wave * 128 + nf * 16 + l15];

    float d1[2][4], d2[2][4];
    int   k1[2][4];
    #pragma unroll
    for (int mf = 0; mf < 2; ++mf)
        #pragma unroll
        for (int r = 0; r < 4; ++r) { d1[mf][r] = 3.402823466e+38f; d2[mf][r] = 3.402823466e+38f; k1[mf][r] = 0; }

    #pragma unroll
    for (int nf = 0; nf < 8; ++nf) {
        const int kc = wave * 128 + nf * 16 + l15;
        #pragma unroll
        for (int mf = 0; mf < 2; ++mf)
            #pragma unroll
            for (int r = 0; r < 4; ++r) {
                const float d = m2v[nf] - 2.0f * acc[mf][nf][r];
                if (d < d1[mf][r]) { d2[mf][r] = d1[mf][r]; d1[mf][r] = d; k1[mf][r] = kc; }
                else if (d < d2[mf][r]) { d2[mf][r] = d; }
            }
    }

    // butterfly across the 16 lanes of each quad; tie -> lower k
    #pragma unroll
    for (int s = 1; s < 16; s <<= 1) {
        #pragma unroll
        for (int mf = 0; mf < 2; ++mf)
            #pragma unroll
            for (int r = 0; r < 4; ++r) {
                const float od1 = __shfl_xor(d1[mf][r], s, 64);
                const int   ok1 = __shfl_xor(k1[mf][r], s, 64);
                const float od2 = __shfl_xor(d2[mf][r], s, 64);
                const bool take = (od1 < d1[mf][r]) || (od1 == d1[mf][r] && ok1 < k1[mf][r]);
                const float loser = take ? d1[mf][r] : od1;
                if (take) { d1[mf][r] = od1; k1[mf][r] = ok1; }
                const float m2x = (od2 < d2[mf][r]) ? od2 : d2[mf][r];
                d2[mf][r] = (loser < m2x) ? loser : m2x;
            }
    }

    if (l15 == 0) {
        #pragma unroll
        for (int mf = 0; mf < 2; ++mf)
            #pragma unroll
            for (int r = 0; r < 4; ++r) {
                const int ml = mf * 16 + q * 4 + r;     // row within tile
                sd1[wave][ml] = d1[mf][r];
                sd2[wave][ml] = d2[mf][r];
                sk1[wave][ml] = k1[mf][r];
            }
    }
    __syncthreads();

    if (tid < 32) {
        float D1 = sd1[0][tid], D2 = sd2[0][tid];
        int   K1 = sk1[0][tid];
        #pragma unroll
        for (int w = 1; w < 4; ++w) {          // ascending wave = ascending k
            const float od1 = sd1[w][tid], od2 = sd2[w][tid];
            const int   ok1 = sk1[w][tid];
            if (od1 < D1) { D2 = (D1 < od2) ? D1 : od2; D1 = od1; K1 = ok1; }
            else          { D2 = (od1 < D2) ? od1 : D2; }
        }
        kb[tid] = K1;
        if (D2 - D1 < TAU) {
            const int i = atomicAdd(&scount, 1);
            slist[i] = tid;                    // local row index
        }
    }
    __syncthreads();

    // ---- fused recon: out rows from muT (L2-hot) ----
    float4* out4 = (float4*)(out + (size_t)m0 * GDIM);
    const float4* muT4 = (const float4*)muT;
    #pragma unroll
    for (int i = 0; i < 8; ++i) {
        const int idx = tid + i * 256;
        const int rr = idx >> 6, cc = idx & 63;
        out4[idx] = muT4[(size_t)kb[rr] * (GDIM / 4) + cc];
    }

    // ---- inline rescue (validated R7/R9-R16): exact R1-order fp32 ----
    // The first barrier below drains the recon stores (vmcnt(0) before
    // s_barrier), so the overwrite is ordered after recon.
    const int cnt = scount;
    for (int i = 0; i < cnt; ++i) {
        const int row = m0 + slist[i];
        xs[tid] = images[(size_t)row * GDIM + tid];
        __syncthreads();
        // x2 in the proven g-ascending serial order
        float x2 = 0.f;
        for (int g = 0; g < GDIM; ++g) x2 += xs[g] * xs[g];
        // codes tid and tid+256: independent g-ascending fp32 chains
        float sA = 0.f, sB = 0.f;
        for (int g = 0; g < GDIM; ++g) {
            const float xv = xs[g];
            const float* mp = mu + (size_t)g * KDIM;
            sA += xv * mp[tid];
            sB += xv * mp[tid + 256];
        }
        const float dA = (x2 - 2.0f * sA) + m2g[tid];
        const float dB = (x2 - 2.0f * sB) + m2g[tid + 256];
        float bd = dA; int bk = tid;
        if (dB < bd) { bd = dB; bk = tid + 256; }      // strict < keeps lower k
        rsd[tid] = bd; rsk[tid] = bk;
        __syncthreads();
        for (int s = 128; s > 0; s >>= 1) {
            if (tid < s) {
                const float db = rsd[tid + s]; const int kb2 = rsk[tid + s];
                if (db < rsd[tid] || (db == rsd[tid] && kb2 < rsk[tid])) { rsd[tid] = db; rsk[tid] = kb2; }
            }
            __syncthreads();
        }
        const int kwin = rsk[0];
        out[(size_t)row * GDIM + tid] = muT[(size_t)kwin * GDIM + tid];
        __syncthreads();
    }
}

// ---------------- fallback (R1 kernel, no workspace) ----------------

constexpr int FROWS = 64, FXSTR = GDIM + 1;

__global__ __launch_bounds__(256)
void kmeans_fallback(const float* __restrict__ images, const float* __restrict__ mu,
                     float* __restrict__ out) {
    __shared__ float xsf[FROWS * FXSTR];
    __shared__ float m2s[KDIM];
    __shared__ float bd_s[4][FROWS];
    __shared__ int   bk_s[4][FROWS];
    __shared__ int   kbest_s[FROWS];
    const int tid = threadIdx.x;
    const long long b0 = (long long)blockIdx.x * FROWS;
    {
        const float4* img4 = (const float4*)(images + b0 * GDIM);
        #pragma unroll
        for (int i = 0; i < 16; ++i) {
            const int idx = tid + i * 256;
            const int r = idx >> 6, c = idx & 63;
            const float4 v = img4[idx];
            float* dst = &xsf[r * FXSTR + c * 4];
            dst[0] = v.x; dst[1] = v.y; dst[2] = v.z; dst[3] = v.w;
        }
    }
    {
        float s0 = 0.f, s1 = 0.f;
        for (int g = 0; g < GDIM; ++g) {
            const float a = mu[(size_t)g * KDIM + tid];
            const float b = mu[(size_t)g * KDIM + tid + 256];
            s0 += a * a; s1 += b * b;
        }
        m2s[tid] = s0; m2s[tid + 256] = s1;
    }
    __syncthreads();
    const int r = tid & (FROWS - 1), ch = tid >> 6;
    const float* xrow = &xsf[r * FXSTR];
    float x2 = 0.f;
    #pragma unroll 8
    for (int g = 0; g < GDIM; ++g) x2 += xrow[g] * xrow[g];
    float bestd = 3.402823466e+38f; int bestk = 0;
    const int k0base = ch * (KDIM / 4);
    for (int kt = 0; kt < KDIM / 4; kt += 8) {
        const int k0 = k0base + kt;
        float a8[8];
        #pragma unroll
        for (int j = 0; j < 8; ++j) a8[j] = 0.f;
        const float* mp = mu + k0;
        #pragma unroll 4
        for (int g = 0; g < GDIM; ++g) {
            const float xv = xrow[g];
            const float4 a = *(const float4*)(mp + (size_t)g * KDIM);
            const float4 b = *(const float4*)(mp + (size_t)g * KDIM + 4);
            a8[0] += xv * a.x; a8[1] += xv * a.y; a8[2] += xv * a.z; a8[3] += xv * a.w;
            a8[4] += xv * b.x; a8[5] += xv * b.y; a8[6] += xv * b.z; a8[7] += xv * b.w;
        }
        #pragma unroll
        for (int j = 0; j < 8; ++j) {
            const float t = x2 - 2.0f * a8[j];
            const float d = t + m2s[k0 + j];
            if (d < bestd) { bestd = d; bestk = k0 + j; }
        }
    }
    bd_s[ch][r] = bestd; bk_s[ch][r] = bestk;
    __syncthreads();
    if (tid < FROWS) {
        float bd = bd_s[0][tid]; int bk = bk_s[0][tid];
        #pragma unroll
        for (int c = 1; c < 4; ++c)
            if (bd_s[c][tid] < bd) { bd = bd_s[c][tid]; bk = bk_s[c][tid]; }
        kbest_s[tid] = bk;
    }
    __syncthreads();
    for (int i = tid; i < FROWS * GDIM; i += 256) {
        const int rr = i >> 8, gg = i & (GDIM - 1);
        out[b0 * GDIM + i] = mu[(size_t)gg * KDIM + kbest_s[rr]];
    }
}

// ---------------- launch ----------------

extern "C" void kernel_launch(void* const* d_in, const int* in_sizes, int n_in,
                              void* d_out, int out_size, void* d_ws, size_t ws_size,
                              hipStream_t stream) {
    const float* images = (const float*)d_in[0];
    const float* mu     = (const float*)d_in[1];
    float* out = (float*)d_out;

    float* ws     = (float*)d_ws;
    float* muT    = ws;                          // 131072 floats
    float* m2     = ws + 131072;                 // 512
    halfx8* packh = (halfx8*)(ws + 131584);      // 65536 floats (16384 vecs)
    halfx8* packl = (halfx8*)(ws + 197120);      // 65536 floats
    const size_t need = (size_t)262656 * sizeof(float);

    if (d_ws != nullptr && ws_size >= need) {
        prep_kernel<<<577, 256, 0, stream>>>(mu, muT, m2, packh, packl);
        gemm_argmin_mfma<<<NTILES, 256, 0, stream>>>(images, mu, packh, packl,
                                                     m2, muT, out);
    } else {
        kmeans_fallback<<<BATCH / 64, 256, 0, stream>>>(images, mu, out);
    }
}